// Round 11
// baseline (448.783 us; speedup 1.0000x reference)
//
#include <hip/hip_runtime.h>
#include <hip/hip_bf16.h>
#include <stdint.h>

#define T_DIM 16
#define B_DIM 4096
#define D_DIM 256
#define H_DIM 512
#define E_DIM 32
#define M_DIM (T_DIM * B_DIM)
#define BD_DIM (B_DIM * D_DIM)     // elems per term/pred slice
#define EPS_F 0.1f

#define NSLICE 16                  // H / SH
#define SH 32                      // h-columns per slice
#define HS_LD 40                   // Hs leading dim (pad 32->40: 16B-aligned b128, bank-spread)
#define MAXS 64

typedef __attribute__((ext_vector_type(8))) short short8;   // 8 bf16 (MFMA A/B frag)
typedef __attribute__((ext_vector_type(4))) float f32x4;    // MFMA C/D frag; clang vec (nontemporal ok)

#define GLOBAL_AS __attribute__((address_space(1)))
#define LDS_AS __attribute__((address_space(3)))

__device__ __forceinline__ uint32_t f2bf_rne(float x) {
  uint32_t u = __float_as_uint(x);
  return (u + 0x7fffu + ((u >> 16) & 1u)) >> 16;
}

// ---- agg v5 (reg-resident term) + prep rider (round-10, byte-identical) ----
__global__ __launch_bounds__(256) void agg_prep_kernel(
    const float* __restrict__ term, const float* __restrict__ pred,
    const float* __restrict__ inv, const float* __restrict__ signs,
    const int* __restrict__ heads, const int* __restrict__ tails,
    const float* __restrict__ W1, const float* __restrict__ W2,
    uint16_t* __restrict__ agg, uint16_t* __restrict__ W1T, uint16_t* __restrict__ W2T) {
  const int tid = threadIdx.x;
  if (blockIdx.x >= 1024) {  // ---- prep path ----
    const int idx = (blockIdx.x - 1024) * 256 + tid;    // 0 .. 131071 == D*H
    const int d = idx >> 9, h = idx & (H_DIM - 1);
    W1T[h * D_DIM + d] = (uint16_t)f2bf_rne(W1[idx]);
    const int h2 = idx >> 8, d2 = idx & (D_DIM - 1);
    W2T[d2 * H_DIM + h2] = (uint16_t)f2bf_rne(W2[idx]);
    return;
  }

  __shared__ float Cm[T_DIM][T_DIM];      // agg[t] = sum_s Cm[t][s]*term[s] + streams
  __shared__ float Lsgn[T_DIM][MAXS];
  __shared__ uint64_t Lptr[T_DIM][MAXS];
  __shared__ int Lcnt[T_DIM];

  Cm[tid >> 4][tid & 15] = ((tid >> 4) == (tid & 15)) ? EPS_F : 0.f;
  if (tid < T_DIM) Lcnt[tid] = 0;
  __syncthreads();
  if (tid < E_DIM) {   // parallel build (round-8 verified)
    const int e = tid;
    const int hh = heads[e] & (T_DIM - 1);
    const int tt = tails[e] & (T_DIM - 1);
    const float s = signs[e];
    atomicAdd(&Cm[tt][hh], s);
    int i = atomicAdd(&Lcnt[tt], 1);
    Lsgn[tt][i] = s; Lptr[tt][i] = (uint64_t)(pred + (size_t)e * BD_DIM);
    atomicAdd(&Cm[hh][tt], s);
    i = atomicAdd(&Lcnt[hh], 1);
    Lsgn[hh][i] = s; Lptr[hh][i] = (uint64_t)(inv + (size_t)e * BD_DIM);
  }
  __syncthreads();

  const int j = (blockIdx.x * 256 + tid) * 4;   // 4-elem chunk in [0, B*D)

  f32x4 tr[T_DIM];
#pragma unroll
  for (int s = 0; s < T_DIM; ++s)
    tr[s] = __builtin_nontemporal_load(reinterpret_cast<const f32x4*>(term + (size_t)s * BD_DIM + j));

#pragma unroll 2
  for (int t = 0; t < T_DIM; ++t) {
    f32x4 cv[4];
#pragma unroll
    for (int q = 0; q < 4; ++q) cv[q] = *reinterpret_cast<const f32x4*>(&Cm[t][q * 4]);

    float acc[4] = {0.f, 0.f, 0.f, 0.f};
#pragma unroll
    for (int s = 0; s < T_DIM; ++s) {
      const float cs = cv[s >> 2][s & 3];
#pragma unroll
      for (int k = 0; k < 4; ++k) acc[k] += cs * tr[s][k];
    }

    const int n = Lcnt[t];
#pragma unroll 2
    for (int i = 0; i < n; ++i) {
      const float sg = Lsgn[t][i];
      const float* bp = (const float*)Lptr[t][i];
      const f32x4 p = __builtin_nontemporal_load(reinterpret_cast<const f32x4*>(bp + j));
#pragma unroll
      for (int k = 0; k < 4; ++k) acc[k] += sg * p[k];
    }

    uint2 pk;
    pk.x = f2bf_rne(acc[0]) | (f2bf_rne(acc[1]) << 16);
    pk.y = f2bf_rne(acc[2]) | (f2bf_rne(acc[3]) << 16);
    *reinterpret_cast<uint2*>(agg + (size_t)t * BD_DIM + j) = pk;
  }
}

// ---- fused MLP v3: W from L2 direct to registers; only As + Hs in LDS ----
// Rationale: W1T/W2T total 512 KB -> fully L2-resident. LDS-staging them forced a
// vmcnt(0) drain at every one of 32 barriers/block (Common-mistake #7: staging data
// that L2-fits). v3 loads W fragments global->reg (compiler pipelines them across
// phases: w1f[s+1] issues during phase B(s), w2f[s] during phase A(s)), and
// double-buffers Hs so each slice needs ONE barrier (write(s+1)&1 vs read(s-1)&1
// are separated by bar(s)). LDS 74 -> 42 KB; barriers 32 -> 16.
__global__ __launch_bounds__(256, 2) void mlp_fused(
    const uint16_t* __restrict__ A,     // agg, [M][256] bf16
    const uint16_t* __restrict__ W1T,   // [H=512][D=256] bf16
    const uint16_t* __restrict__ W2T,   // [D=256][H=512] bf16
    const float* __restrict__ b1, const float* __restrict__ b2,
    float* __restrict__ Out) {
  __shared__ __align__(16) uint16_t As[64 * 256];       // 32 KB, [kc=0..7][row=0..63][32]
  __shared__ __align__(16) uint16_t Hs[2][64 * HS_LD];  // 2 x 5 KB

  const int tid = threadIdx.x;
  const int w = tid >> 6;
  const int l = tid & 63;
  const int lane16 = l & 15;
  const int quad = l >> 4;
  const int m0 = blockIdx.x * 64;

  const int wm  = (w & 1) * 32;
  const int wnA = ((w >> 1) & 1) * 16;
  const int wn2 = ((w >> 1) & 1) * 128;

  // ---- stage A-chunk; LDS dest == linear byte off (gload_lds contract) ----
#pragma unroll
  for (int p = 0; p < 8; ++p) {
    const int off = p * 2048 + tid * 8;          // == kc*2048 + row*32 + c
    const int kc = off >> 11;
    const int row = (off >> 5) & 63;
    const int c = off & 31;
    const uint16_t* g = A + (size_t)(m0 + row) * D_DIM + kc * 32 + c;
    __builtin_amdgcn_global_load_lds((const GLOBAL_AS uint32_t*)g,
                                     (LDS_AS uint32_t*)(As + off), 16, 0, 0);
  }

  // ---- prologue: W1 fragments for slice 0, global (L2) -> regs ----
  short8 w1f[8];
#pragma unroll
  for (int kk = 0; kk < 8; ++kk)
    w1f[kk] = *reinterpret_cast<const short8*>(
        W1T + (size_t)(wnA + lane16) * D_DIM + kk * 32 + quad * 8);

  __syncthreads();   // As resident (drains the staged loads once)

  f32x4 oacc[2][8];
#pragma unroll
  for (int i = 0; i < 2; ++i)
#pragma unroll
    for (int j = 0; j < 8; ++j) oacc[i][j] = (f32x4){0.f, 0.f, 0.f, 0.f};

  for (int s = 0; s < NSLICE; ++s) {
    // W2 fragments for slice s (independent of phase A; compiler interleaves with MFMA)
    short8 w2f[8];
#pragma unroll
    for (int j = 0; j < 8; ++j)
      w2f[j] = *reinterpret_cast<const short8*>(
          W2T + (size_t)(wn2 + j * 16 + lane16) * H_DIM + s * SH + quad * 8);

    // ===== phase A(s): hacc = As x W1_s =====
    f32x4 hacc[2];
#pragma unroll
    for (int i = 0; i < 2; ++i) hacc[i] = (f32x4){0.f, 0.f, 0.f, 0.f};
#pragma unroll
    for (int kk = 0; kk < 8; ++kk) {
      short8 af[2];
#pragma unroll
      for (int i = 0; i < 2; ++i)
        af[i] = *reinterpret_cast<const short8*>(As + kk * 2048 + (wm + i * 16 + lane16) * 32 + quad * 8);
#pragma unroll
      for (int i = 0; i < 2; ++i)
        hacc[i] = __builtin_amdgcn_mfma_f32_16x16x32_bf16(af[i], w1f[kk], hacc[i], 0, 0, 0);
    }

    // bias+relu -> Hs[s&1]
    {
      const int hloc = wnA + lane16;
      const float bv = b1[s * SH + hloc];
      uint16_t* hsb = Hs[s & 1];
#pragma unroll
      for (int i = 0; i < 2; ++i) {
#pragma unroll
        for (int r = 0; r < 4; ++r) {
          const int row = wm + i * 16 + quad * 4 + r;
          const float x = fmaxf(hacc[i][r] + bv, 0.f);
          hsb[row * HS_LD + hloc] = (uint16_t)f2bf_rne(x);
        }
      }
    }
    __syncthreads();   // the ONLY barrier per slice: Hs[s&1] visible to all waves

    // reload W1 fragments for slice s+1 (regs free after phase A; overlaps phase B)
    if (s < NSLICE - 1) {
#pragma unroll
      for (int kk = 0; kk < 8; ++kk)
        w1f[kk] = *reinterpret_cast<const short8*>(
            W1T + (size_t)((s + 1) * SH + wnA + lane16) * D_DIM + kk * 32 + quad * 8);
    }

    // ===== phase B(s): oacc += Hs[s&1] x W2_s =====
    {
      const uint16_t* hsb = Hs[s & 1];
      short8 af2[2];
#pragma unroll
      for (int i = 0; i < 2; ++i)
        af2[i] = *reinterpret_cast<const short8*>(hsb + (wm + i * 16 + lane16) * HS_LD + quad * 8);
#pragma unroll
      for (int i = 0; i < 2; ++i)
#pragma unroll
        for (int j = 0; j < 8; ++j)
          oacc[i][j] = __builtin_amdgcn_mfma_f32_16x16x32_bf16(af2[i], w2f[j], oacc[i][j], 0, 0, 0);
    }
    // no second barrier: next slice writes Hs[(s+1)&1] (other buffer); the previous
    // reader of that buffer (phase B(s-1)) is separated from it by THIS slice's barrier.
  }

  // ---- final epilogue ----
#pragma unroll
  for (int j = 0; j < 8; ++j) {
    const int col = wn2 + j * 16 + lane16;
    const float bv = b2[col];
#pragma unroll
    for (int i = 0; i < 2; ++i) {
#pragma unroll
      for (int r = 0; r < 4; ++r) {
        const int row = m0 + wm + i * 16 + quad * 4 + r;
        Out[(size_t)row * D_DIM + col] = oacc[i][j][r] + bv;
      }
    }
  }
}

extern "C" void kernel_launch(void* const* d_in, const int* in_sizes, int n_in,
                              void* d_out, int out_size, void* d_ws, size_t ws_size,
                              hipStream_t stream) {
  const float* term  = (const float*)d_in[0];
  const float* pred  = (const float*)d_in[1];
  const float* inv   = (const float*)d_in[2];
  const float* signs = (const float*)d_in[3];
  const float* W1    = (const float*)d_in[4];
  const float* b1    = (const float*)d_in[5];
  const float* W2    = (const float*)d_in[6];
  const float* b2    = (const float*)d_in[7];
  const int* heads   = (const int*)d_in[8];
  const int* tails   = (const int*)d_in[9];

  char* ws = (char*)d_ws;
  uint16_t* W1T = (uint16_t*)(ws);              // 256 KB
  uint16_t* W2T = (uint16_t*)(ws + 262144);     // 256 KB
  uint16_t* agg = (uint16_t*)(ws + 524288);     // 32 MB

  // dispatch 1: agg v5 (blocks 0..1023) + prep (blocks 1024..1535)
  agg_prep_kernel<<<dim3(1536), dim3(256), 0, stream>>>(
      term, pred, inv, signs, heads, tails, W1, W2, agg, W1T, W2T);
  // dispatch 2: fused MLP v3 (W from L2, 16 barriers, 42 KB LDS)
  mlp_fused<<<dim3(M_DIM / 64), dim3(256), 0, stream>>>(
      agg, W1T, W2T, b1, b2, (float*)d_out);
}

// Round 12
// 389.751 us; speedup vs baseline: 1.1515x; 1.1515x over previous
//
#include <hip/hip_runtime.h>
#include <hip/hip_bf16.h>
#include <stdint.h>

#define T_DIM 16
#define B_DIM 4096
#define D_DIM 256
#define H_DIM 512
#define E_DIM 32
#define M_DIM (T_DIM * B_DIM)
#define BD_DIM (B_DIM * D_DIM)     // elems per term/pred slice
#define EPS_F 0.1f

#define NSLICE 16                  // H / SH
#define SH 32                      // h-columns per slice
#define HS_LD 40                   // Hs leading dim (pad 32->40: 16B-aligned b128, bank-spread)
#define MAXS 64

typedef __attribute__((ext_vector_type(8))) short short8;   // 8 bf16 (MFMA A/B frag)
typedef __attribute__((ext_vector_type(4))) float f32x4;    // MFMA C/D frag; clang vec (nontemporal ok)

#define GLOBAL_AS __attribute__((address_space(1)))
#define LDS_AS __attribute__((address_space(3)))

__device__ __forceinline__ uint32_t f2bf_rne(float x) {
  uint32_t u = __float_as_uint(x);
  return (u + 0x7fffu + ((u >> 16) & 1u)) >> 16;
}

// ---- agg v5 (reg-resident term) + prep rider (round-10, byte-identical) ----
__global__ __launch_bounds__(256) void agg_prep_kernel(
    const float* __restrict__ term, const float* __restrict__ pred,
    const float* __restrict__ inv, const float* __restrict__ signs,
    const int* __restrict__ heads, const int* __restrict__ tails,
    const float* __restrict__ W1, const float* __restrict__ W2,
    uint16_t* __restrict__ agg, uint16_t* __restrict__ W1T, uint16_t* __restrict__ W2T) {
  const int tid = threadIdx.x;
  if (blockIdx.x >= 1024) {  // ---- prep path ----
    const int idx = (blockIdx.x - 1024) * 256 + tid;    // 0 .. 131071 == D*H
    const int d = idx >> 9, h = idx & (H_DIM - 1);
    W1T[h * D_DIM + d] = (uint16_t)f2bf_rne(W1[idx]);
    const int h2 = idx >> 8, d2 = idx & (D_DIM - 1);
    W2T[d2 * H_DIM + h2] = (uint16_t)f2bf_rne(W2[idx]);
    return;
  }

  __shared__ float Cm[T_DIM][T_DIM];      // agg[t] = sum_s Cm[t][s]*term[s] + streams
  __shared__ float Lsgn[T_DIM][MAXS];
  __shared__ uint64_t Lptr[T_DIM][MAXS];
  __shared__ int Lcnt[T_DIM];

  Cm[tid >> 4][tid & 15] = ((tid >> 4) == (tid & 15)) ? EPS_F : 0.f;
  if (tid < T_DIM) Lcnt[tid] = 0;
  __syncthreads();
  if (tid < E_DIM) {   // parallel build (round-8 verified)
    const int e = tid;
    const int hh = heads[e] & (T_DIM - 1);
    const int tt = tails[e] & (T_DIM - 1);
    const float s = signs[e];
    atomicAdd(&Cm[tt][hh], s);
    int i = atomicAdd(&Lcnt[tt], 1);
    Lsgn[tt][i] = s; Lptr[tt][i] = (uint64_t)(pred + (size_t)e * BD_DIM);
    atomicAdd(&Cm[hh][tt], s);
    i = atomicAdd(&Lcnt[hh], 1);
    Lsgn[hh][i] = s; Lptr[hh][i] = (uint64_t)(inv + (size_t)e * BD_DIM);
  }
  __syncthreads();

  const int j = (blockIdx.x * 256 + tid) * 4;   // 4-elem chunk in [0, B*D)

  f32x4 tr[T_DIM];
#pragma unroll
  for (int s = 0; s < T_DIM; ++s)
    tr[s] = __builtin_nontemporal_load(reinterpret_cast<const f32x4*>(term + (size_t)s * BD_DIM + j));

#pragma unroll 2
  for (int t = 0; t < T_DIM; ++t) {
    f32x4 cv[4];
#pragma unroll
    for (int q = 0; q < 4; ++q) cv[q] = *reinterpret_cast<const f32x4*>(&Cm[t][q * 4]);

    float acc[4] = {0.f, 0.f, 0.f, 0.f};
#pragma unroll
    for (int s = 0; s < T_DIM; ++s) {
      const float cs = cv[s >> 2][s & 3];
#pragma unroll
      for (int k = 0; k < 4; ++k) acc[k] += cs * tr[s][k];
    }

    const int n = Lcnt[t];
#pragma unroll 2
    for (int i = 0; i < n; ++i) {
      const float sg = Lsgn[t][i];
      const float* bp = (const float*)Lptr[t][i];
      const f32x4 p = __builtin_nontemporal_load(reinterpret_cast<const f32x4*>(bp + j));
#pragma unroll
      for (int k = 0; k < 4; ++k) acc[k] += sg * p[k];
    }

    uint2 pk;
    pk.x = f2bf_rne(acc[0]) | (f2bf_rne(acc[1]) << 16);
    pk.y = f2bf_rne(acc[2]) | (f2bf_rne(acc[3]) << 16);
    *reinterpret_cast<uint2*>(agg + (size_t)t * BD_DIM + j) = pk;
  }
}

// ---- fused MLP v4: A in registers; W coop-staged (coalesced, v2-proven); ----
// ---- all LDS buffers double-buffered; ONE barrier per slice (17 total vs v2's 33) ----
// v3 post-mortem: per-slice strided W reg-gathers from L2 were the regression (latency
// chain, phases too short to hide). v4 keeps v2's coalesced global_load_lds staging but
// rotates the loop to {bar; issue stages; B(s); A(s+1)} with Wb1/Wb2/Hs all x2:
//   - stage W2[s+1]->Wb2[(s+1)&1]: prior reader B(s-1) ended before bar(s); drained by
//     bar(s+1); read by B(s+1). Full-slice prefetch distance.
//   - stage W1[s+2]->Wb1[s&1]: prior reader A(s) ended before bar(s); drained by
//     bar(s+1); read by A(s+2) at end of iter s+1.
//   - A(x) writes Hs[x&1]; prior reader B(x-2) ended one barrier earlier; B(s) reads
//     Hs[s&1] written by A(s) before bar(s).
// A-tile: af[2][8] regs (64 VGPR), loaded once from L3-resident agg; As LDS deleted.
// LDS = 2x16 (Wb1) + 2x16 (Wb2) + 2x5 (Hs) = 74 KB -> 2 blocks/CU.
__global__ __launch_bounds__(256, 2) void mlp_fused(
    const uint16_t* __restrict__ A,     // agg, [M][256] bf16
    const uint16_t* __restrict__ W1T,   // [H=512][D=256] bf16
    const uint16_t* __restrict__ W2T,   // [D=256][H=512] bf16
    const float* __restrict__ b1, const float* __restrict__ b2,
    float* __restrict__ Out) {
  __shared__ __align__(16) uint16_t Wb1[2][SH * 256];   // [kc=0..7][hl=0..31][32]
  __shared__ __align__(16) uint16_t Wb2[2][SH * 256];   // [d=0..255][32]
  __shared__ __align__(16) uint16_t Hs[2][64 * HS_LD];

  const int tid = threadIdx.x;
  const int w = tid >> 6;
  const int l = tid & 63;
  const int lane16 = l & 15;
  const int quad = l >> 4;
  const int m0 = blockIdx.x * 64;

  const int wm  = (w & 1) * 32;
  const int wnA = ((w >> 1) & 1) * 16;
  const int wn2 = ((w >> 1) & 1) * 128;

#define STAGE_W1(sl, buf)                                                           \
  {                                                                                 \
    _Pragma("unroll")                                                               \
    for (int p = 0; p < 4; ++p) {                                                   \
      const int off = p * 2048 + tid * 8; /* == kc*1024 + hl*32 + c */              \
      const int kc = off >> 10;                                                     \
      const int hl = (off >> 5) & 31;                                               \
      const int c = off & 31;                                                       \
      const uint16_t* g = W1T + (size_t)((sl) * SH + hl) * D_DIM + kc * 32 + c;     \
      __builtin_amdgcn_global_load_lds((const GLOBAL_AS uint32_t*)g,                \
                                       (LDS_AS uint32_t*)(Wb1[buf] + off), 16, 0, 0); \
    }                                                                               \
  }
#define STAGE_W2(sl, buf)                                                           \
  {                                                                                 \
    _Pragma("unroll")                                                               \
    for (int p = 0; p < 4; ++p) {                                                   \
      const int off = p * 2048 + tid * 8; /* == d*32 + c */                         \
      const int d = off >> 5;                                                       \
      const int c = off & 31;                                                       \
      const uint16_t* g = W2T + (size_t)d * H_DIM + (sl) * SH + c;                  \
      __builtin_amdgcn_global_load_lds((const GLOBAL_AS uint32_t*)g,                \
                                       (LDS_AS uint32_t*)(Wb2[buf] + off), 16, 0, 0); \
    }                                                                               \
  }

  // ---- prologue stages: W1[0]->Wb1[0], W1[1]->Wb1[1], W2[0]->Wb2[0] ----
  STAGE_W1(0, 0);
  STAGE_W1(1, 1);
  STAGE_W2(0, 0);

  // ---- A-tile -> registers: af[i][kk] = A[m0+wm+i*16+lane16][kk*32+quad*8 ..+7] ----
  short8 af[2][8];
#pragma unroll
  for (int i = 0; i < 2; ++i)
#pragma unroll
    for (int kk = 0; kk < 8; ++kk)
      af[i][kk] = *reinterpret_cast<const short8*>(
          A + (size_t)(m0 + wm + i * 16 + lane16) * D_DIM + kk * 32 + quad * 8);

  f32x4 oacc[2][8];
#pragma unroll
  for (int i = 0; i < 2; ++i)
#pragma unroll
    for (int j = 0; j < 8; ++j) oacc[i][j] = (f32x4){0.f, 0.f, 0.f, 0.f};

  __syncthreads();   // prologue stages drained; af resident

  // ---- phase A(sl): hacc = af x Wb1[sl&1]; bias+relu -> Hs[sl&1] ----
#define PHASE_A(sl)                                                                 \
  {                                                                                 \
    f32x4 hacc[2];                                                                  \
    _Pragma("unroll")                                                               \
    for (int i = 0; i < 2; ++i) hacc[i] = (f32x4){0.f, 0.f, 0.f, 0.f};              \
    const uint16_t* wb = Wb1[(sl) & 1];                                             \
    _Pragma("unroll")                                                               \
    for (int kk = 0; kk < 8; ++kk) {                                                \
      const short8 bfr = *reinterpret_cast<const short8*>(                          \
          wb + kk * 1024 + (wnA + lane16) * 32 + quad * 8);                         \
      _Pragma("unroll")                                                             \
      for (int i = 0; i < 2; ++i)                                                   \
        hacc[i] = __builtin_amdgcn_mfma_f32_16x16x32_bf16(af[i][kk], bfr, hacc[i], 0, 0, 0); \
    }                                                                               \
    const int hloc = wnA + lane16;                                                  \
    const float bv = b1[(sl) * SH + hloc];                                          \
    uint16_t* hsb = Hs[(sl) & 1];                                                   \
    _Pragma("unroll")                                                               \
    for (int i = 0; i < 2; ++i) {                                                   \
      _Pragma("unroll")                                                             \
      for (int r = 0; r < 4; ++r) {                                                 \
        const int row = wm + i * 16 + quad * 4 + r;                                 \
        const float x = fmaxf(hacc[i][r] + bv, 0.f);                                \
        hsb[row * HS_LD + hloc] = (uint16_t)f2bf_rne(x);                            \
      }                                                                             \
    }                                                                               \
  }

  PHASE_A(0);

  for (int s = 0; s < NSLICE; ++s) {
    __syncthreads();   // Hs[s&1] + Wb2[s&1] (+ Wb1[(s+1)&1]) all resident

    if (s + 2 <= NSLICE - 1) STAGE_W1(s + 2, s & 1);
    if (s + 1 <= NSLICE - 1) STAGE_W2(s + 1, (s + 1) & 1);

    // ===== phase B(s): oacc += Hs[s&1] x Wb2[s&1] =====
    {
      const uint16_t* hsb = Hs[s & 1];
      const uint16_t* wb = Wb2[s & 1];
      short8 af2[2], w2f[8];
#pragma unroll
      for (int i = 0; i < 2; ++i)
        af2[i] = *reinterpret_cast<const short8*>(hsb + (wm + i * 16 + lane16) * HS_LD + quad * 8);
#pragma unroll
      for (int j = 0; j < 8; ++j)
        w2f[j] = *reinterpret_cast<const short8*>(wb + (wn2 + j * 16 + lane16) * 32 + quad * 8);
#pragma unroll
      for (int i = 0; i < 2; ++i)
#pragma unroll
        for (int j = 0; j < 8; ++j)
          oacc[i][j] = __builtin_amdgcn_mfma_f32_16x16x32_bf16(af2[i], w2f[j], oacc[i][j], 0, 0, 0);
    }

    if (s + 1 <= NSLICE - 1) PHASE_A(s + 1);
  }

  // ---- final epilogue ----
#pragma unroll
  for (int j = 0; j < 8; ++j) {
    const int col = wn2 + j * 16 + lane16;
    const float bv = b2[col];
#pragma unroll
    for (int i = 0; i < 2; ++i) {
#pragma unroll
      for (int r = 0; r < 4; ++r) {
        const int row = m0 + wm + i * 16 + quad * 4 + r;
        Out[(size_t)row * D_DIM + col] = oacc[i][j][r] + bv;
      }
    }
  }
#undef STAGE_W1
#undef STAGE_W2
#undef PHASE_A
}

extern "C" void kernel_launch(void* const* d_in, const int* in_sizes, int n_in,
                              void* d_out, int out_size, void* d_ws, size_t ws_size,
                              hipStream_t stream) {
  const float* term  = (const float*)d_in[0];
  const float* pred  = (const float*)d_in[1];
  const float* inv   = (const float*)d_in[2];
  const float* signs = (const float*)d_in[3];
  const float* W1    = (const float*)d_in[4];
  const float* b1    = (const float*)d_in[5];
  const float* W2    = (const float*)d_in[6];
  const float* b2    = (const float*)d_in[7];
  const int* heads   = (const int*)d_in[8];
  const int* tails   = (const int*)d_in[9];

  char* ws = (char*)d_ws;
  uint16_t* W1T = (uint16_t*)(ws);              // 256 KB
  uint16_t* W2T = (uint16_t*)(ws + 262144);     // 256 KB
  uint16_t* agg = (uint16_t*)(ws + 524288);     // 32 MB

  // dispatch 1: agg v5 (blocks 0..1023) + prep (blocks 1024..1535)
  agg_prep_kernel<<<dim3(1536), dim3(256), 0, stream>>>(
      term, pred, inv, signs, heads, tails, W1, W2, agg, W1T, W2T);
  // dispatch 2: fused MLP v4 (A in regs, 1 barrier/slice, full dbuf)
  mlp_fused<<<dim3(M_DIM / 64), dim3(256), 0, stream>>>(
      agg, W1T, W2T, b1, b2, (float*)d_out);
}